// Round 14
// baseline (138.451 us; speedup 1.0000x reference)
//
#include <hip/hip_runtime.h>
#include <math.h>

// NoiseGenerator: out[n][b] = (y1[n][b] - y2[n][b]) * env[n][b]   (gain folded into y)
//   y1[n] = f_lp*y1[n-1] + (1-f_lp)*gain*noise[n]
//   y2[n] = f_hp*y2[n-1] + (1-f_hp)*y1[n]          (highpass = y1 - y2)
//   env[n] = (1 - exp(-t/(attack+eps))) * exp(-t/(decay+eps)), t = n/48000
//
// Round 14 == round-8 design, nontemporal-store type fixed (ext_vector_type,
// since __builtin_nontemporal_store rejects HIP_vector_type float4):
//   kC runs 960 blocks (3.75 waves/SIMD): block (g,h) loads entry state of
//   group g; h=1 re-advances 25 samples (pure recurrence, no stores —
//   bitwise identical to h=0's first half), then writes its 25 rows with
//   nontemporal 16B stores.
//   kB: KB_COLS=8 -> 128 blocks staging, LDS 30.7 KB.

#define NSAMP   24000
#define NBATCH  1024
#define SPT     50             // group length (scan granularity)
#define HALF    25             // kC rows per block
#define NGRP    480            // NSAMP / SPT
#define CPT     4              // columns per thread -> 16B stores
#define TPB     256            // 256*4 = 1024 cols -> block spans all columns
#define EPSF    1e-4f
#define DT      (1.0f/48000.0f)

typedef float f32x4 __attribute__((ext_vector_type(4)));   // clang vector: ok for nontemporal builtin

// ---------------- Phase A: group aggregates (zero entry state) ----------------
__global__ __launch_bounds__(TPB) void kA_aggr(const float* __restrict__ par,
                                               const float* __restrict__ noise,
                                               float* __restrict__ gv1,
                                               float* __restrict__ gv2) {
    const int g    = blockIdx.x;
    const int col0 = threadIdx.x * CPT;
    const int n0   = g * SPT;

    const float4 flp = *reinterpret_cast<const float4*>(&par[2 * NBATCH + col0]);
    const float4 fhp = *reinterpret_cast<const float4*>(&par[3 * NBATCH + col0]);
    const float4 gn  = *reinterpret_cast<const float4*>(&par[4 * NBATCH + col0]);

    float a1[CPT], c1[CPT], a2[CPT], c2[CPT], y1[CPT], y2[CPT];
#pragma unroll
    for (int k = 0; k < CPT; ++k) {
        a1[k] = (&flp.x)[k];
        a2[k] = (&fhp.x)[k];
        c1[k] = (1.0f - a1[k]) * (&gn.x)[k];         // gain folded in (matches kC)
        c2[k] = 1.0f - a2[k];
        y1[k] = 0.0f; y2[k] = 0.0f;
    }

#pragma unroll 10
    for (int i = 0; i < SPT; ++i) {
        const float x = noise[n0 + i];               // block-uniform -> s_load
#pragma unroll
        for (int k = 0; k < CPT; ++k) {
            y1[k] = a1[k] * y1[k] + c1[k] * x;
            y2[k] = a2[k] * y2[k] + c2[k] * y1[k];
        }
    }
    *reinterpret_cast<float4*>(&gv1[g * NBATCH + col0]) = make_float4(y1[0], y1[1], y1[2], y1[3]);
    *reinterpret_cast<float4*>(&gv2[g * NBATCH + col0]) = make_float4(y2[0], y2[1], y2[2], y2[3]);
}

// ---------------- Phase B: LDS-staged per-column scan over groups ----------------
#define KB_COLS 8              // columns per block; LDS = 480*8*4*2 = 30.7 KB
__global__ __launch_bounds__(256) void kB_scan(const float* __restrict__ par,
                                               float* __restrict__ gv1,
                                               float* __restrict__ gv2) {
    __shared__ float l1[NGRP][KB_COLS];
    __shared__ float l2[NGRP][KB_COLS];
    const int col0 = blockIdx.x * KB_COLS;           // 128 blocks
    const int j    = threadIdx.x & (KB_COLS - 1);
    const int r0   = threadIdx.x >> 3;               // 32 rows per pass, 15 passes

    // stage: 256 threads, independent loads; LDS write = 2 lanes/bank (free)
#pragma unroll 5
    for (int r = r0; r < NGRP; r += 32) {
        l1[r][j] = gv1[r * NBATCH + col0 + j];
        l2[r][j] = gv2[r * NBATCH + col0 + j];
    }
    __syncthreads();

    if (threadIdx.x < KB_COLS) {
        const int b = col0 + j;
        const float a1 = par[2 * NBATCH + b];
        const float a2 = par[3 * NBATCH + b];
        const float c2 = 1.0f - a2;

        // M^SPT via homogeneous recurrence (cancellation-safe when f_lp ~ f_hp):
        float u1 = 1.0f, u2 = 0.0f, u3 = 1.0f;
#pragma unroll 10
        for (int i = 0; i < SPT; ++i) {
            u1 = a1 * u1;
            u2 = a2 * u2 + c2 * u1;
            u3 = a2 * u3;
        }
        const float p1 = u1, mL = u2, p2 = u3;

        float s1 = 0.0f, s2 = 0.0f;                  // entry state of group 0
#pragma unroll 8
        for (int c = 0; c < NGRP; ++c) {
            const float v1 = l1[c][j];
            const float v2 = l2[c][j];
            l1[c][j] = s1;                           // overwrite aggregate with entry
            l2[c][j] = s2;
            const float w  = mL * s1 + v2;           // off the s2 critical chain
            s1 = p1 * s1 + v1;                       // two short FMA chains
            s2 = p2 * s2 + w;
        }
    }
    __syncthreads();

    // writeback entry states
#pragma unroll 5
    for (int r = r0; r < NGRP; r += 32) {
        gv1[r * NBATCH + col0 + j] = l1[r][j];
        gv2[r * NBATCH + col0 + j] = l2[r][j];
    }
}

// ---------------- Phase C: output half-groups with envelope ----------------
__global__ __launch_bounds__(TPB) void kC_out(const float* __restrict__ par,
                                              const float* __restrict__ noise,
                                              const float* __restrict__ gv1,
                                              const float* __restrict__ gv2,
                                              float* __restrict__ out) {
    const int g    = blockIdx.x;                     // group 0..479
    const int h    = blockIdx.y;                     // half 0..1
    const int col0 = threadIdx.x * CPT;
    const int ng   = g * SPT;                        // group start sample
    const int n0   = ng + h * HALF;                  // this block's first output row

    const float4 att4 = *reinterpret_cast<const float4*>(&par[0 * NBATCH + col0]);
    const float4 dec4 = *reinterpret_cast<const float4*>(&par[1 * NBATCH + col0]);
    const float4 flp  = *reinterpret_cast<const float4*>(&par[2 * NBATCH + col0]);
    const float4 fhp  = *reinterpret_cast<const float4*>(&par[3 * NBATCH + col0]);
    const float4 gn   = *reinterpret_cast<const float4*>(&par[4 * NBATCH + col0]);
    const float4 e1   = *reinterpret_cast<const float4*>(&gv1[g * NBATCH + col0]);
    const float4 e2   = *reinterpret_cast<const float4*>(&gv2[g * NBATCH + col0]);

    float a1[CPT], c1[CPT], a2[CPT], c2[CPT], y1[CPT], y2[CPT];
    float ea[CPT], ra[CPT], ed[CPT], rd[CPT];
    const float t0 = (float)n0 * DT;

#pragma unroll
    for (int k = 0; k < CPT; ++k) {
        const float ia  = 1.0f / ((&att4.x)[k] + EPSF);
        const float idc = 1.0f / ((&dec4.x)[k] + EPSF);
        a1[k] = (&flp.x)[k];
        a2[k] = (&fhp.x)[k];
        c1[k] = (1.0f - a1[k]) * (&gn.x)[k];
        c2[k] = 1.0f - a2[k];
        ea[k] = expf(-t0 * ia);   ra[k] = expf(-DT * ia);   // re-anchored per half-group
        ed[k] = expf(-t0 * idc);  rd[k] = expf(-DT * idc);
        y1[k] = (&e1.x)[k];                                 // exact group-entry state
        y2[k] = (&e2.x)[k];
    }

    // h=1: advance 25 samples from group entry (identical ops to h=0's half ->
    // bitwise-equal state), no env, no stores. ~250 cycles.
    if (h) {
#pragma unroll 5
        for (int i = 0; i < HALF; ++i) {
            const float x = noise[ng + i];
#pragma unroll
            for (int k = 0; k < CPT; ++k) {
                y1[k] = a1[k] * y1[k] + c1[k] * x;
                y2[k] = a2[k] * y2[k] + c2[k] * y1[k];
            }
        }
    }

    f32x4* op = reinterpret_cast<f32x4*>(out + (size_t)n0 * NBATCH + col0);
#pragma unroll 5
    for (int i = 0; i < HALF; ++i) {
        const float x = noise[n0 + i];               // block-uniform -> s_load
        f32x4 o;
#pragma unroll
        for (int k = 0; k < CPT; ++k) {
            y1[k] = a1[k] * y1[k] + c1[k] * x;
            y2[k] = a2[k] * y2[k] + c2[k] * y1[k];
            const float env = (1.0f - ea[k]) * ed[k];
            o[k] = (y1[k] - y2[k]) * env;
            ea[k] *= ra[k];
            ed[k] *= rd[k];
        }
        __builtin_nontemporal_store(o, op);          // never re-read: bypass cache
        op += NBATCH / 4;
    }
}

extern "C" void kernel_launch(void* const* d_in, const int* in_sizes, int n_in,
                              void* d_out, int out_size, void* d_ws, size_t ws_size,
                              hipStream_t stream) {
    const float* par   = (const float*)d_in[0];   // [5, 1024]
    const float* noise = (const float*)d_in[1];   // [24000]
    float* out = (float*)d_out;                   // [24000, 1024]
    float* gv1 = (float*)d_ws;                    // [NGRP][NBATCH]
    float* gv2 = gv1 + (size_t)NGRP * NBATCH;     // [NGRP][NBATCH]  (~4 MB total)

    kA_aggr<<<dim3(NGRP), dim3(TPB), 0, stream>>>(par, noise, gv1, gv2);
    kB_scan<<<dim3(NBATCH / KB_COLS), dim3(256), 0, stream>>>(par, gv1, gv2);
    kC_out <<<dim3(NGRP, 2), dim3(TPB), 0, stream>>>(par, noise, gv1, gv2, out);
}